// Round 1
// baseline (369.631 us; speedup 1.0000x reference)
//
#include <hip/hip_runtime.h>
#include <hip/hip_bf16.h>
#include <cstdint>

#define TT   8192
#define KOBS 512
#define HID  2048
#define NOBJ 8
#define NCH  64     // number of time chunks
#define CT   128    // chunk length (TT / NCH)

typedef unsigned short u16;
typedef short bf16x8 __attribute__((ext_vector_type(8)));
typedef float f32x4  __attribute__((ext_vector_type(4)));

static __device__ __forceinline__ float bf2f(u16 u) {
    union { uint32_t i; float f; } v;
    v.i = ((uint32_t)u) << 16;
    return v.f;
}
static __device__ __forceinline__ u16 f2bf(float f) {
    union { float f; uint32_t i; } v;
    v.f = f;
    uint32_t lsb = (v.i >> 16) & 1u;
    uint32_t r = v.i + 0x7fffu + lsb;   // round-to-nearest-even
    return (u16)(r >> 16);
}

// ---------------------------------------------------------------------------
// Kernel 1: cast x -> bf16; cast + row-interleave the 4 weight matrices
// (W_cat row n = 4*h + proj, proj: 0=W_in 1=W_B 2=W_C 3=W_delta);
// precompute A_e[h] = -exp(A_log[h]) * log2(e).
// ---------------------------------------------------------------------------
__global__ void prep_kernel(const float* __restrict__ x,
                            const float* __restrict__ Win,
                            const float* __restrict__ WB,
                            const float* __restrict__ WC,
                            const float* __restrict__ Wd,
                            const float* __restrict__ A_log,
                            u16* __restrict__ x_bf,
                            u16* __restrict__ W_bf,
                            float* __restrict__ A_e)
{
    const int64_t NX = (int64_t)TT * KOBS;      // 4,194,304
    const int64_t NW = (int64_t)4 * HID * KOBS; // 4,194,304
    int64_t i = (int64_t)blockIdx.x * blockDim.x + threadIdx.x;
    int64_t stride = (int64_t)gridDim.x * blockDim.x;

    for (int64_t t = i; t < NX; t += stride) x_bf[t] = f2bf(x[t]);

    for (int64_t t = i; t < NW; t += stride) {
        int n = (int)(t >> 9);          // /512  -> interleaved row
        int k = (int)(t & 511);
        int h = n >> 2;
        int w = n & 3;                  // wave-uniform (512 consecutive t share n)
        const float* src = (w == 0) ? Win : (w == 1) ? WB : (w == 2) ? WC : Wd;
        W_bf[t] = f2bf(src[(int64_t)h * KOBS + k]);
    }

    for (int64_t t = i; t < HID; t += stride)
        A_e[t] = -__expf(A_log[t]) * 1.44269504f;
}

// ---------------------------------------------------------------------------
// Kernel 2: bf16 MFMA GEMM  [8192 x 512] x [512 x 8192]^T  (both K-major)
// 128x128 block tile, BK=32, 4 waves of 64x64 (4x4 MFMA 16x16x32 tiles).
// Fused epilogue: lanes hold proj = lane&3 for channel h = n>>2; one
// shfl_xor(1) pairs x_state with B. Emits (bf16):
//   LA[t,h] = sigmoid(dlogit) * A_e[h]   (log2-domain decay)
//   BX[t,h] = B * x_state
//   CC[t,h] = C
// ---------------------------------------------------------------------------
__launch_bounds__(256)
__global__ void gemm_fused(const u16* __restrict__ x_bf,
                           const u16* __restrict__ W_bf,
                           const float* __restrict__ A_e,
                           u16* __restrict__ LA,
                           u16* __restrict__ BX,
                           u16* __restrict__ CC)
{
    __shared__ __align__(16) u16 a_s[128 * 40];   // pad 32->40 elems (2-way max)
    __shared__ __align__(16) u16 b_s[128 * 40];

    const int tid  = threadIdx.x;
    const int bm   = blockIdx.x & 63;
    const int bn   = blockIdx.x >> 6;
    const int m0   = bm * 128;
    const int n0   = bn * 128;
    const int lane = tid & 63;
    const int wave = tid >> 6;
    const int wm   = (wave & 1) * 64;
    const int wn   = (wave >> 1) * 64;
    const int fr   = lane & 15;     // free index within 16-tile
    const int fq   = lane >> 4;     // quad -> k offset 8*fq, rows 4*fq..4*fq+3

    f32x4 acc[4][4];
#pragma unroll
    for (int i = 0; i < 4; i++)
#pragma unroll
        for (int j = 0; j < 4; j++) {
            f32x4 z = {0.f, 0.f, 0.f, 0.f};
            acc[i][j] = z;
        }

    const int ldrow = tid >> 2;        // 0..63
    const int ldc   = (tid & 3) * 8;   // element offset within 32-wide K tile

    for (int kb = 0; kb < KOBS; kb += 32) {
#pragma unroll
        for (int rr = 0; rr < 2; rr++) {
            int r = rr * 64 + ldrow;
            const u16* ga = x_bf + (size_t)(m0 + r) * KOBS + kb + ldc;
            *(uint4*)&a_s[r * 40 + ldc] = *(const uint4*)ga;
            const u16* gb = W_bf + (size_t)(n0 + r) * KOBS + kb + ldc;
            *(uint4*)&b_s[r * 40 + ldc] = *(const uint4*)gb;
        }
        __syncthreads();

        bf16x8 af[4], bfr[4];
#pragma unroll
        for (int i = 0; i < 4; i++)
            af[i] = *(const bf16x8*)&a_s[(wm + i * 16 + fr) * 40 + fq * 8];
#pragma unroll
        for (int j = 0; j < 4; j++)
            bfr[j] = *(const bf16x8*)&b_s[(wn + j * 16 + fr) * 40 + fq * 8];

#pragma unroll
        for (int i = 0; i < 4; i++)
#pragma unroll
            for (int j = 0; j < 4; j++)
                acc[i][j] = __builtin_amdgcn_mfma_f32_16x16x32_bf16(
                    af[i], bfr[j], acc[i][j], 0, 0, 0);
        __syncthreads();
    }

    // Epilogue. C/D layout: col = lane&15 (= n), row = 4*(lane>>4) + reg.
    const int jp = lane & 3;           // projection of this lane's column
#pragma unroll
    for (int i = 0; i < 4; i++) {
        const int trow_base = m0 + wm + i * 16 + fq * 4;
#pragma unroll
        for (int j = 0; j < 4; j++) {
            const int n = n0 + wn + j * 16 + fr;
            const int h = n >> 2;
            const float ae = A_e[h];
#pragma unroll
            for (int reg = 0; reg < 4; reg++) {
                const int t = trow_base + reg;
                const float v = acc[i][j][reg];
                const float s1 = __shfl_xor(v, 1, 64);  // pair (xs<->B), (C<->dl)
                const size_t off = (size_t)t * HID + h;
                if (jp == 0) {
                    BX[off] = f2bf(v * s1);             // x_state * B
                } else if (jp == 2) {
                    CC[off] = f2bf(v);                  // C
                } else if (jp == 3) {
                    float sig = 1.0f / (1.0f + __expf(-v));
                    LA[off] = f2bf(sig * ae);           // delta*A*log2e
                }
            }
        }
    }
}

// ---------------------------------------------------------------------------
// Kernel 3: chunked scan pass 1 — per (channel, chunk): P = prod a, S = scan
// value assuming h0 = 0.  a = exp2(LA).
// ---------------------------------------------------------------------------
__global__ void scan_pass1(const u16* __restrict__ LA,
                           const u16* __restrict__ BX,
                           float* __restrict__ P,
                           float* __restrict__ S)
{
    const int c = blockIdx.x >> 3;                       // chunk 0..63
    const int h = ((blockIdx.x & 7) << 8) + threadIdx.x; // channel 0..2047
    float p = 1.f, s = 0.f;
    size_t base = (size_t)c * CT * HID + h;
    for (int t = 0; t < CT; t++) {
        float a  = exp2f(bf2f(LA[base]));
        float bx = bf2f(BX[base]);
        s = fmaf(a, s, bx);
        p *= a;
        base += HID;
    }
    P[c * HID + h] = p;
    S[c * HID + h] = s;
}

// ---------------------------------------------------------------------------
// Kernel 4: sequential combine across 64 chunks per channel -> H0[c,h]
// ---------------------------------------------------------------------------
__global__ void scan_combine(const float* __restrict__ P,
                             const float* __restrict__ S,
                             float* __restrict__ H0)
{
    const int h = blockIdx.x * 256 + threadIdx.x;
    float hrun = 0.f;
    for (int c = 0; c < NCH; c++) {
        H0[c * HID + h] = hrun;
        hrun = fmaf(P[c * HID + h], hrun, S[c * HID + h]);
    }
}

// ---------------------------------------------------------------------------
// Kernel 5: pass 2 — re-scan each chunk from its true h0; y = C*h (fp32)
// ---------------------------------------------------------------------------
__global__ void scan_pass2(const u16* __restrict__ LA,
                           const u16* __restrict__ BX,
                           const u16* __restrict__ CC,
                           const float* __restrict__ H0,
                           float* __restrict__ Y)
{
    const int c = blockIdx.x >> 3;
    const int h = ((blockIdx.x & 7) << 8) + threadIdx.x;
    float hrun = H0[c * HID + h];
    size_t base = (size_t)c * CT * HID + h;
    for (int t = 0; t < CT; t++) {
        float a  = exp2f(bf2f(LA[base]));
        float bx = bf2f(BX[base]);
        hrun = fmaf(a, hrun, bx);
        Y[base] = bf2f(CC[base]) * hrun;
        base += HID;
    }
}

// ---------------------------------------------------------------------------
// Kernel 6: out[t,:] = Y[t,:] @ W_out.T + x[t,:] @ W_skip.T + b_out  (fp32)
// One block (256 thr) per t row; LDS tree reduction.
// ---------------------------------------------------------------------------
__launch_bounds__(256)
__global__ void out_kernel(const float* __restrict__ Y,
                           const float* __restrict__ x,
                           const float* __restrict__ W_out,
                           const float* __restrict__ b_out,
                           const float* __restrict__ W_skip,
                           float* __restrict__ out)
{
    const int t = blockIdx.x;
    const int tid = threadIdx.x;
    float acc[NOBJ];
#pragma unroll
    for (int o = 0; o < NOBJ; o++) acc[o] = 0.f;

    for (int h = tid; h < HID; h += 256) {
        float y = Y[(size_t)t * HID + h];
#pragma unroll
        for (int o = 0; o < NOBJ; o++)
            acc[o] = fmaf(y, W_out[o * HID + h], acc[o]);
    }
    for (int k = tid; k < KOBS; k += 256) {
        float xv = x[(size_t)t * KOBS + k];
#pragma unroll
        for (int o = 0; o < NOBJ; o++)
            acc[o] = fmaf(xv, W_skip[o * KOBS + k], acc[o]);
    }

    __shared__ float red[NOBJ * 256];
#pragma unroll
    for (int o = 0; o < NOBJ; o++) red[o * 256 + tid] = acc[o];
    __syncthreads();
    for (int s = 128; s > 0; s >>= 1) {
        if (tid < s) {
#pragma unroll
            for (int o = 0; o < NOBJ; o++)
                red[o * 256 + tid] += red[o * 256 + tid + s];
        }
        __syncthreads();
    }
    if (tid < NOBJ)
        out[(size_t)t * NOBJ + tid] = red[tid * 256] + b_out[tid];
}

// ---------------------------------------------------------------------------
extern "C" void kernel_launch(void* const* d_in, const int* in_sizes, int n_in,
                              void* d_out, int out_size, void* d_ws, size_t ws_size,
                              hipStream_t stream)
{
    const float* x      = (const float*)d_in[0];
    const float* Win    = (const float*)d_in[1];
    const float* WB     = (const float*)d_in[2];
    const float* WC     = (const float*)d_in[3];
    const float* Wd     = (const float*)d_in[4];
    const float* A_log  = (const float*)d_in[5];
    const float* W_out  = (const float*)d_in[6];
    const float* b_out  = (const float*)d_in[7];
    const float* W_skip = (const float*)d_in[8];
    float* out = (float*)d_out;

    char* ws = (char*)d_ws;
    size_t off = 0;
    auto alloc = [&](size_t bytes) -> void* {
        void* p = (void*)(ws + off);
        off += (bytes + 255) & ~(size_t)255;
        return p;
    };

    u16*   x_bf = (u16*)  alloc((size_t)TT * KOBS * 2);        //  8.4 MB
    u16*   W_bf = (u16*)  alloc((size_t)4 * HID * KOBS * 2);   //  8.4 MB
    float* A_e  = (float*)alloc((size_t)HID * 4);              //  8 KB
    u16*   LA   = (u16*)  alloc((size_t)TT * HID * 2);         // 33.6 MB
    u16*   BX   = (u16*)  alloc((size_t)TT * HID * 2);         // 33.6 MB
    u16*   CC   = (u16*)  alloc((size_t)TT * HID * 2);         // 33.6 MB
    float* P    = (float*)alloc((size_t)NCH * HID * 4);        //  0.5 MB
    float* S    = (float*)alloc((size_t)NCH * HID * 4);        //  0.5 MB
    float* H0   = (float*)alloc((size_t)NCH * HID * 4);        //  0.5 MB
    float* Y    = (float*)alloc((size_t)TT * HID * 4);         // 67.1 MB
    (void)ws_size; (void)in_sizes; (void)n_in; (void)out_size; // ~186 MB total

    prep_kernel<<<2048, 256, 0, stream>>>(x, Win, WB, WC, Wd, A_log,
                                          x_bf, W_bf, A_e);
    gemm_fused<<<4096, 256, 0, stream>>>(x_bf, W_bf, A_e, LA, BX, CC);
    scan_pass1<<<512, 256, 0, stream>>>(LA, BX, P, S);
    scan_combine<<<8, 256, 0, stream>>>(P, S, H0);
    scan_pass2<<<512, 256, 0, stream>>>(LA, BX, CC, H0, Y);
    out_kernel<<<TT, 256, 0, stream>>>(Y, x, W_out, b_out, W_skip, out);
}

// Round 2
// 345.774 us; speedup vs baseline: 1.0690x; 1.0690x over previous
//
#include <hip/hip_runtime.h>
#include <hip/hip_bf16.h>
#include <cstdint>

#define TT   8192
#define KOBS 512
#define HID  2048
#define NOBJ 8
#define NCH  64     // number of time chunks
#define CT   128    // chunk length (TT / NCH)

typedef unsigned short u16;
typedef short bf16x8 __attribute__((ext_vector_type(8)));
typedef float f32x4  __attribute__((ext_vector_type(4)));

static __device__ __forceinline__ float bf2f(u16 u) {
    union { uint32_t i; float f; } v;
    v.i = ((uint32_t)u) << 16;
    return v.f;
}
static __device__ __forceinline__ u16 f2bf(float f) {
    union { float f; uint32_t i; } v;
    v.f = f;
    uint32_t lsb = (v.i >> 16) & 1u;
    uint32_t r = v.i + 0x7fffu + lsb;   // round-to-nearest-even
    return (u16)(r >> 16);
}

// async global->LDS DMA, 16 bytes per lane. LDS dest MUST be
// wave-uniform-base + lane*16 (no per-lane scatter).
static __device__ __forceinline__ void async_ld16(const u16* g, u16* l) {
    __builtin_amdgcn_global_load_lds(
        (const __attribute__((address_space(1))) uint32_t*)g,
        (__attribute__((address_space(3))) uint32_t*)l,
        16, 0, 0);
}

// ---------------------------------------------------------------------------
// Kernel 1: cast x -> bf16; cast + row-interleave the 4 weight matrices
// (W_cat row n = 4*h + proj, proj: 0=W_in 1=W_B 2=W_C 3=W_delta);
// precompute A_e[h] = -exp(A_log[h]) * log2(e).
// ---------------------------------------------------------------------------
__global__ void prep_kernel(const float* __restrict__ x,
                            const float* __restrict__ Win,
                            const float* __restrict__ WB,
                            const float* __restrict__ WC,
                            const float* __restrict__ Wd,
                            const float* __restrict__ A_log,
                            u16* __restrict__ x_bf,
                            u16* __restrict__ W_bf,
                            float* __restrict__ A_e)
{
    const int64_t NX = (int64_t)TT * KOBS;      // 4,194,304
    const int64_t NW = (int64_t)4 * HID * KOBS; // 4,194,304
    int64_t i = (int64_t)blockIdx.x * blockDim.x + threadIdx.x;
    int64_t stride = (int64_t)gridDim.x * blockDim.x;

    for (int64_t t = i; t < NX; t += stride) x_bf[t] = f2bf(x[t]);

    for (int64_t t = i; t < NW; t += stride) {
        int n = (int)(t >> 9);          // /512  -> interleaved row
        int k = (int)(t & 511);
        int h = n >> 2;
        int w = n & 3;                  // wave-uniform (512 consecutive t share n)
        const float* src = (w == 0) ? Win : (w == 1) ? WB : (w == 2) ? WC : Wd;
        W_bf[t] = f2bf(src[(int64_t)h * KOBS + k]);
    }

    for (int64_t t = i; t < HID; t += stride)
        A_e[t] = -__expf(A_log[t]) * 1.44269504f;
}

// ---------------------------------------------------------------------------
// Kernel 2: bf16 MFMA GEMM  [8192 x 512] x [512 x 8192]^T  (both K-major)
// 128x128 block tile, BK=32, 4 waves of 64x64 (4x4 MFMA 16x16x32 tiles).
// Staging via global_load_lds (16B/lane DMA, no VGPR round trip).
// LDS layout: unpadded 128 rows x 32 cols with XOR col-group swizzle
//   phys_cg = cg ^ ((row>>1)&3)   (self-inverse; applied at stage & read)
// -> ds_read_b128 bank-quads all distinct within a 16-lane phase.
// Fused epilogue unchanged from round 1 (verified correct).
// ---------------------------------------------------------------------------
__launch_bounds__(256)
__global__ void gemm_fused(const u16* __restrict__ x_bf,
                           const u16* __restrict__ W_bf,
                           const float* __restrict__ A_e,
                           u16* __restrict__ LA,
                           u16* __restrict__ BX,
                           u16* __restrict__ CC)
{
    __shared__ __align__(16) u16 a_s[128 * 32];   // 8 KB
    __shared__ __align__(16) u16 b_s[128 * 32];   // 8 KB

    const int tid  = threadIdx.x;
    const int bm   = blockIdx.x & 63;
    const int bn   = blockIdx.x >> 6;
    const int m0   = bm * 128;
    const int n0   = bn * 128;
    const int lane = tid & 63;
    const int wave = tid >> 6;
    const int wm   = (wave & 1) * 64;
    const int wn   = (wave >> 1) * 64;
    const int fr   = lane & 15;     // free index within 16-tile
    const int fq   = lane >> 4;     // quad -> k offset 8*fq

    f32x4 acc[4][4];
#pragma unroll
    for (int i = 0; i < 4; i++)
#pragma unroll
        for (int j = 0; j < 4; j++) {
            f32x4 z = {0.f, 0.f, 0.f, 0.f};
            acc[i][j] = z;
        }

    // ---- staging addressing (DMA): thread tid fills LDS bytes [tid*16, +16)
    // LDS slot (row = tid>>2, phys col-group = tid&3) must hold global
    // col-group (tid&3) ^ ((row>>1)&3).
    const int srow = tid >> 2;                       // 0..63
    const int scg  = (tid & 3) ^ ((srow >> 1) & 3);  // swizzled source col grp
    // note: row+64 has identical ((row>>1)&3), so same scg for second half
    const u16* gA0 = x_bf + (size_t)(m0 + srow) * KOBS + scg * 8;
    const u16* gA1 = gA0 + (size_t)64 * KOBS;
    const u16* gB0 = W_bf + (size_t)(n0 + srow) * KOBS + scg * 8;
    const u16* gB1 = gB0 + (size_t)64 * KOBS;
    u16* lA0 = &a_s[tid * 8];
    u16* lA1 = &a_s[2048 + tid * 8];
    u16* lB0 = &b_s[tid * 8];
    u16* lB1 = &b_s[2048 + tid * 8];

    // ---- fragment-read addressing: phys col-group for this lane.
    // (row>>1)&3 == (fr>>1)&3 for every tile (wm, 16*i multiples of 8).
    const int pcg = fq ^ ((fr >> 1) & 3);

    for (int kb = 0; kb < KOBS; kb += 32) {
        async_ld16(gA0 + kb, lA0);
        async_ld16(gA1 + kb, lA1);
        async_ld16(gB0 + kb, lB0);
        async_ld16(gB1 + kb, lB1);
        __syncthreads();

        bf16x8 af[4], bfr[4];
#pragma unroll
        for (int i = 0; i < 4; i++)
            af[i] = *(const bf16x8*)&a_s[(wm + i * 16 + fr) * 32 + pcg * 8];
#pragma unroll
        for (int j = 0; j < 4; j++)
            bfr[j] = *(const bf16x8*)&b_s[(wn + j * 16 + fr) * 32 + pcg * 8];

#pragma unroll
        for (int i = 0; i < 4; i++)
#pragma unroll
            for (int j = 0; j < 4; j++)
                acc[i][j] = __builtin_amdgcn_mfma_f32_16x16x32_bf16(
                    af[i], bfr[j], acc[i][j], 0, 0, 0);
        __syncthreads();
    }

    // Epilogue. C/D layout: col = lane&15 (= n), row = 4*(lane>>4) + reg.
    const int jp = lane & 3;           // projection of this lane's column
#pragma unroll
    for (int i = 0; i < 4; i++) {
        const int trow_base = m0 + wm + i * 16 + fq * 4;
#pragma unroll
        for (int j = 0; j < 4; j++) {
            const int n = n0 + wn + j * 16 + fr;
            const int h = n >> 2;
            const float ae = A_e[h];
#pragma unroll
            for (int reg = 0; reg < 4; reg++) {
                const int t = trow_base + reg;
                const float v = acc[i][j][reg];
                const float s1 = __shfl_xor(v, 1, 64);  // pair (xs<->B), (C<->dl)
                const size_t off = (size_t)t * HID + h;
                if (jp == 0) {
                    BX[off] = f2bf(v * s1);             // x_state * B
                } else if (jp == 2) {
                    CC[off] = f2bf(v);                  // C
                } else if (jp == 3) {
                    float sig = 1.0f / (1.0f + __expf(-v));
                    LA[off] = f2bf(sig * ae);           // delta*A*log2e
                }
            }
        }
    }
}

// ---------------------------------------------------------------------------
// Kernel 3: chunked scan pass 1 — per (channel, chunk): P = prod a, S = scan
// value assuming h0 = 0.  a = exp2(LA).
// ---------------------------------------------------------------------------
__global__ void scan_pass1(const u16* __restrict__ LA,
                           const u16* __restrict__ BX,
                           float* __restrict__ P,
                           float* __restrict__ S)
{
    const int c = blockIdx.x >> 3;                       // chunk 0..63
    const int h = ((blockIdx.x & 7) << 8) + threadIdx.x; // channel 0..2047
    float p = 1.f, s = 0.f;
    size_t base = (size_t)c * CT * HID + h;
    for (int t = 0; t < CT; t++) {
        float a  = exp2f(bf2f(LA[base]));
        float bx = bf2f(BX[base]);
        s = fmaf(a, s, bx);
        p *= a;
        base += HID;
    }
    P[c * HID + h] = p;
    S[c * HID + h] = s;
}

// ---------------------------------------------------------------------------
// Kernel 4: sequential combine across 64 chunks per channel -> H0[c,h]
// ---------------------------------------------------------------------------
__global__ void scan_combine(const float* __restrict__ P,
                             const float* __restrict__ S,
                             float* __restrict__ H0)
{
    const int h = blockIdx.x * 256 + threadIdx.x;
    float hrun = 0.f;
    for (int c = 0; c < NCH; c++) {
        H0[c * HID + h] = hrun;
        hrun = fmaf(P[c * HID + h], hrun, S[c * HID + h]);
    }
}

// ---------------------------------------------------------------------------
// Kernel 5: pass 2 — re-scan each chunk from its true h0; y = C*h (fp32)
// ---------------------------------------------------------------------------
__global__ void scan_pass2(const u16* __restrict__ LA,
                           const u16* __restrict__ BX,
                           const u16* __restrict__ CC,
                           const float* __restrict__ H0,
                           float* __restrict__ Y)
{
    const int c = blockIdx.x >> 3;
    const int h = ((blockIdx.x & 7) << 8) + threadIdx.x;
    float hrun = H0[c * HID + h];
    size_t base = (size_t)c * CT * HID + h;
    for (int t = 0; t < CT; t++) {
        float a  = exp2f(bf2f(LA[base]));
        float bx = bf2f(BX[base]);
        hrun = fmaf(a, hrun, bx);
        Y[base] = bf2f(CC[base]) * hrun;
        base += HID;
    }
}

// ---------------------------------------------------------------------------
// Kernel 6: out[t,:] = Y[t,:] @ W_out.T + x[t,:] @ W_skip.T + b_out  (fp32)
// One wave per 4 t-rows; W tiles held in registers (amortized 4x);
// shuffle-only butterfly reduction (no barriers).
// ---------------------------------------------------------------------------
__launch_bounds__(256)
__global__ void out_kernel(const float* __restrict__ Y,
                           const float* __restrict__ x,
                           const float* __restrict__ W_out,
                           const float* __restrict__ b_out,
                           const float* __restrict__ W_skip,
                           float* __restrict__ out)
{
    const int wave = threadIdx.x >> 6;
    const int lane = threadIdx.x & 63;
    const int t0 = (blockIdx.x * 4 + wave) * 4;     // 4 t-rows per wave

    float acc[4][NOBJ];
#pragma unroll
    for (int tt = 0; tt < 4; tt++)
#pragma unroll
        for (int o = 0; o < NOBJ; o++) acc[tt][o] = 0.f;

    // hidden part: HID/4 = 512 float4 per row, 64 lanes -> 8 iters
#pragma unroll 2
    for (int i = 0; i < 8; i++) {
        const int hv = (i * 64 + lane) * 4;
        float4 w[NOBJ];
#pragma unroll
        for (int o = 0; o < NOBJ; o++)
            w[o] = *(const float4*)(W_out + (size_t)o * HID + hv);
#pragma unroll
        for (int tt = 0; tt < 4; tt++) {
            float4 y = *(const float4*)(Y + (size_t)(t0 + tt) * HID + hv);
#pragma unroll
            for (int o = 0; o < NOBJ; o++)
                acc[tt][o] += y.x * w[o].x + y.y * w[o].y +
                              y.z * w[o].z + y.w * w[o].w;
        }
    }
    // skip part: KOBS/4 = 128 float4 per row -> 2 iters
#pragma unroll
    for (int i = 0; i < 2; i++) {
        const int kv = (i * 64 + lane) * 4;
        float4 w[NOBJ];
#pragma unroll
        for (int o = 0; o < NOBJ; o++)
            w[o] = *(const float4*)(W_skip + (size_t)o * KOBS + kv);
#pragma unroll
        for (int tt = 0; tt < 4; tt++) {
            float4 xv = *(const float4*)(x + (size_t)(t0 + tt) * KOBS + kv);
#pragma unroll
            for (int o = 0; o < NOBJ; o++)
                acc[tt][o] += xv.x * w[o].x + xv.y * w[o].y +
                              xv.z * w[o].z + xv.w * w[o].w;
        }
    }

    // butterfly reduce across 64 lanes
#pragma unroll
    for (int s = 32; s > 0; s >>= 1)
#pragma unroll
        for (int tt = 0; tt < 4; tt++)
#pragma unroll
            for (int o = 0; o < NOBJ; o++)
                acc[tt][o] += __shfl_xor(acc[tt][o], s, 64);

    if (lane == 0) {
#pragma unroll
        for (int tt = 0; tt < 4; tt++)
#pragma unroll
            for (int o = 0; o < NOBJ; o++)
                out[(size_t)(t0 + tt) * NOBJ + o] = acc[tt][o] + b_out[o];
    }
}

// ---------------------------------------------------------------------------
extern "C" void kernel_launch(void* const* d_in, const int* in_sizes, int n_in,
                              void* d_out, int out_size, void* d_ws, size_t ws_size,
                              hipStream_t stream)
{
    const float* x      = (const float*)d_in[0];
    const float* Win    = (const float*)d_in[1];
    const float* WB     = (const float*)d_in[2];
    const float* WC     = (const float*)d_in[3];
    const float* Wd     = (const float*)d_in[4];
    const float* A_log  = (const float*)d_in[5];
    const float* W_out  = (const float*)d_in[6];
    const float* b_out  = (const float*)d_in[7];
    const float* W_skip = (const float*)d_in[8];
    float* out = (float*)d_out;

    char* ws = (char*)d_ws;
    size_t off = 0;
    auto alloc = [&](size_t bytes) -> void* {
        void* p = (void*)(ws + off);
        off += (bytes + 255) & ~(size_t)255;
        return p;
    };

    u16*   x_bf = (u16*)  alloc((size_t)TT * KOBS * 2);        //  8.4 MB
    u16*   W_bf = (u16*)  alloc((size_t)4 * HID * KOBS * 2);   //  8.4 MB
    float* A_e  = (float*)alloc((size_t)HID * 4);              //  8 KB
    u16*   LA   = (u16*)  alloc((size_t)TT * HID * 2);         // 33.6 MB
    u16*   BX   = (u16*)  alloc((size_t)TT * HID * 2);         // 33.6 MB
    u16*   CC   = (u16*)  alloc((size_t)TT * HID * 2);         // 33.6 MB
    float* P    = (float*)alloc((size_t)NCH * HID * 4);        //  0.5 MB
    float* S    = (float*)alloc((size_t)NCH * HID * 4);        //  0.5 MB
    float* H0   = (float*)alloc((size_t)NCH * HID * 4);        //  0.5 MB
    float* Y    = (float*)alloc((size_t)TT * HID * 4);         // 67.1 MB
    (void)ws_size; (void)in_sizes; (void)n_in; (void)out_size; // ~186 MB total

    prep_kernel<<<2048, 256, 0, stream>>>(x, Win, WB, WC, Wd, A_log,
                                          x_bf, W_bf, A_e);
    gemm_fused<<<4096, 256, 0, stream>>>(x_bf, W_bf, A_e, LA, BX, CC);
    scan_pass1<<<512, 256, 0, stream>>>(LA, BX, P, S);
    scan_combine<<<8, 256, 0, stream>>>(P, S, H0);
    scan_pass2<<<512, 256, 0, stream>>>(LA, BX, CC, H0, Y);
    out_kernel<<<512, 256, 0, stream>>>(Y, x, W_out, b_out, W_skip, out);
}

// Round 3
// 236.332 us; speedup vs baseline: 1.5640x; 1.4631x over previous
//
#include <hip/hip_runtime.h>
#include <hip/hip_bf16.h>
#include <cstdint>

#define TT   8192
#define KOBS 512
#define HID  2048
#define NOBJ 8
#define NCH  64     // number of time chunks
#define CT   128    // chunk length (TT / NCH)

typedef unsigned short u16;
typedef short bf16x8 __attribute__((ext_vector_type(8)));
typedef float f32x4  __attribute__((ext_vector_type(4)));
typedef unsigned short u16x4 __attribute__((ext_vector_type(4)));

static __device__ __forceinline__ float bf2f(u16 u) {
    union { uint32_t i; float f; } v;
    v.i = ((uint32_t)u) << 16;
    return v.f;
}
static __device__ __forceinline__ u16 f2bf(float f) {
    union { float f; uint32_t i; } v;
    v.f = f;
    uint32_t lsb = (v.i >> 16) & 1u;
    uint32_t r = v.i + 0x7fffu + lsb;   // round-to-nearest-even
    return (u16)(r >> 16);
}

// async global->LDS DMA, 16 bytes per lane. LDS dest MUST be
// wave-uniform-base + lane*16 (no per-lane scatter).
static __device__ __forceinline__ void async_ld16(const u16* g, u16* l) {
    __builtin_amdgcn_global_load_lds(
        (const __attribute__((address_space(1))) uint32_t*)g,
        (__attribute__((address_space(3))) uint32_t*)l,
        16, 0, 0);
}

// ---------------------------------------------------------------------------
// Kernel 1: cast x -> bf16; cast + row-interleave the 4 weight matrices
// (W_cat row n = 4*h + proj, proj: 0=W_in 1=W_B 2=W_C 3=W_delta);
// precompute A_e[h] = -exp(A_log[h]) * log2(e).
// ---------------------------------------------------------------------------
__global__ void prep_kernel(const float* __restrict__ x,
                            const float* __restrict__ Win,
                            const float* __restrict__ WB,
                            const float* __restrict__ WC,
                            const float* __restrict__ Wd,
                            const float* __restrict__ A_log,
                            u16* __restrict__ x_bf,
                            u16* __restrict__ W_bf,
                            float* __restrict__ A_e)
{
    const int64_t NX = (int64_t)TT * KOBS;      // 4,194,304
    const int64_t NW = (int64_t)4 * HID * KOBS; // 4,194,304
    int64_t i = (int64_t)blockIdx.x * blockDim.x + threadIdx.x;
    int64_t stride = (int64_t)gridDim.x * blockDim.x;

    for (int64_t t = i; t < NX; t += stride) x_bf[t] = f2bf(x[t]);

    for (int64_t t = i; t < NW; t += stride) {
        int n = (int)(t >> 9);          // /512  -> interleaved row
        int k = (int)(t & 511);
        int h = n >> 2;
        int w = n & 3;                  // wave-uniform (512 consecutive t share n)
        const float* src = (w == 0) ? Win : (w == 1) ? WB : (w == 2) ? WC : Wd;
        W_bf[t] = f2bf(src[(int64_t)h * KOBS + k]);
    }

    for (int64_t t = i; t < HID; t += stride)
        A_e[t] = -__expf(A_log[t]) * 1.44269504f;
}

// ---------------------------------------------------------------------------
// Kernel 2: fused GEMM + elementwise + scan-pass1.
//  - A operand := W fragments  -> D row (4*fq+reg) = n (channel dim):
//    reg 0..3 = the 4 projections of channel h = all in ONE lane.
//  - Epilogue: per lane compute bx/cc/la; u16 -> LDS ep[3][128][40];
//    read back ds_read_b128, store packed 16B to global [t][h].
//  - Scan pass1: block tile (128 t x 32 h) == chunk bm; compute P,S
//    per (chunk, h) from LDS ep directly (8 segments x 16 steps + combine).
// ---------------------------------------------------------------------------
__launch_bounds__(256)
__global__ void gemm_fused(const u16* __restrict__ x_bf,
                           const u16* __restrict__ W_bf,
                           const float* __restrict__ A_e,
                           u16* __restrict__ BX,
                           u16* __restrict__ CC,
                           u16* __restrict__ LA,
                           float* __restrict__ P,
                           float* __restrict__ S)
{
    // union: K-loop staging (16 KB) / epilogue transpose buffer (30 KB)
    __shared__ __align__(16) u16 smem[3 * 128 * 40];   // 30720 B
    __shared__ float Ps[256], Ss[256];                 //  2 KB
    u16* a_s = smem;            // x tile: 128 t-rows x 32 k
    u16* b_s = smem + 4096;     // W tile: 128 n-rows x 32 k

    const int tid  = threadIdx.x;
    const int bm   = blockIdx.x & 63;    // t-chunk (== scan chunk c)
    const int bn   = blockIdx.x >> 6;    // channel group (32 h)
    const int m0t  = bm * 128;
    const int n0   = bn * 128;
    const int lane = tid & 63;
    const int wave = tid >> 6;
    const int wn   = (wave & 1) * 64;    // n-dim wave offset
    const int wt   = (wave >> 1) * 64;   // t-dim wave offset
    const int fr   = lane & 15;
    const int fq   = lane >> 4;

    f32x4 acc[4][4];
#pragma unroll
    for (int i = 0; i < 4; i++)
#pragma unroll
        for (int j = 0; j < 4; j++) {
            f32x4 z = {0.f, 0.f, 0.f, 0.f};
            acc[i][j] = z;
        }

    // staging (DMA): thread tid fills LDS bytes [tid*16, +16) of each half
    const int srow = tid >> 2;                       // 0..63
    const int scg  = (tid & 3) ^ ((srow >> 1) & 3);  // XOR col-group swizzle
    const u16* gA0 = x_bf + (size_t)(m0t + srow) * KOBS + scg * 8;
    const u16* gA1 = gA0 + (size_t)64 * KOBS;
    const u16* gB0 = W_bf + (size_t)(n0 + srow) * KOBS + scg * 8;
    const u16* gB1 = gB0 + (size_t)64 * KOBS;
    u16* lA0 = &a_s[tid * 8];
    u16* lA1 = &a_s[2048 + tid * 8];
    u16* lB0 = &b_s[tid * 8];
    u16* lB1 = &b_s[2048 + tid * 8];

    const int pcg = fq ^ ((fr >> 1) & 3);  // fragment-read swizzled col-group

    for (int kb = 0; kb < KOBS; kb += 32) {
        async_ld16(gA0 + kb, lA0);
        async_ld16(gA1 + kb, lA1);
        async_ld16(gB0 + kb, lB0);
        async_ld16(gB1 + kb, lB1);
        __syncthreads();

        bf16x8 af[4], bfx[4];
#pragma unroll
        for (int i = 0; i < 4; i++)    // A operand = W rows (n-dim)
            af[i] = *(const bf16x8*)&b_s[(wn + i * 16 + fr) * 32 + pcg * 8];
#pragma unroll
        for (int j = 0; j < 4; j++)    // B operand = x rows (t-dim)
            bfx[j] = *(const bf16x8*)&a_s[(wt + j * 16 + fr) * 32 + pcg * 8];

#pragma unroll
        for (int i = 0; i < 4; i++)
#pragma unroll
            for (int j = 0; j < 4; j++)
                acc[i][j] = __builtin_amdgcn_mfma_f32_16x16x32_bf16(
                    af[i], bfx[j], acc[i][j], 0, 0, 0);
        __syncthreads();
    }

    // ---- epilogue: D row = n_local = wn + i*16 + 4*fq + reg (reg = proj),
    //                D col = t_local = wt + j*16 + fr.
    const int hq = wn >> 2;                  // 0 or 16
#pragma unroll
    for (int i = 0; i < 4; i++) {
        const int hl = hq + i * 4 + fq;      // h_local 0..31
        const float ae = A_e[bn * 32 + hl];
#pragma unroll
        for (int j = 0; j < 4; j++) {
            const int tl = wt + j * 16 + fr;
            f32x4 v = acc[i][j];
            float sig = 1.0f / (1.0f + __expf(-v[3]));
            smem[(0 * 128 + tl) * 40 + hl] = f2bf(v[0] * v[1]);  // BX
            smem[(1 * 128 + tl) * 40 + hl] = f2bf(v[2]);         // CC
            smem[(2 * 128 + tl) * 40 + hl] = f2bf(sig * ae);     // LA
        }
    }
    __syncthreads();

    // ---- packed global stores: 384 chunks (a,t) of 64 B, 6 iters
#pragma unroll
    for (int it = 0; it < 6; it++) {
        const int g = it * 64 + (tid >> 2);
        const int a = g >> 7;
        const int t = g & 127;
        const int c = tid & 3;
        uint4 vd = *(const uint4*)&smem[(a * 128 + t) * 40 + c * 8];
        u16* dst = (a == 0 ? BX : (a == 1 ? CC : LA)) +
                   (size_t)(m0t + t) * HID + bn * 32 + c * 8;
        *(uint4*)dst = vd;
    }

    // ---- fused scan pass1: 8 segments x 16 steps, then serial combine
    {
        const int hi  = tid & 31;
        const int seg = tid >> 5;
        float p = 1.f, s = 0.f;
        const int tbase = seg * 16;
#pragma unroll
        for (int t = 0; t < 16; t++) {
            float a  = exp2f(bf2f(smem[(2 * 128 + tbase + t) * 40 + hi]));
            float bx = bf2f(smem[(0 * 128 + tbase + t) * 40 + hi]);
            s = fmaf(a, s, bx);
            p *= a;
        }
        Ps[seg * 32 + hi] = p;
        Ss[seg * 32 + hi] = s;
        __syncthreads();
        if (tid < 32) {
            float pt = 1.f, st = 0.f;
#pragma unroll
            for (int sg = 0; sg < 8; sg++) {
                float ps = Ps[sg * 32 + tid], ss = Ss[sg * 32 + tid];
                st = fmaf(ps, st, ss);
                pt *= ps;
            }
            P[(size_t)bm * HID + bn * 32 + tid] = pt;
            S[(size_t)bm * HID + bn * 32 + tid] = st;
        }
    }
}

// ---------------------------------------------------------------------------
// Kernel 3: sequential combine across 64 chunks per channel -> H0[c,h]
// ---------------------------------------------------------------------------
__global__ void scan_combine(const float* __restrict__ P,
                             const float* __restrict__ S,
                             float* __restrict__ H0)
{
    const int h = blockIdx.x * 256 + threadIdx.x;
    float hrun = 0.f;
    for (int c = 0; c < NCH; c++) {
        H0[c * HID + h] = hrun;
        hrun = fmaf(P[c * HID + h], hrun, S[c * HID + h]);
    }
}

// ---------------------------------------------------------------------------
// Kernel 4: pass 2 — re-scan each chunk from its true h0; Y = C*h (bf16)
// ---------------------------------------------------------------------------
__global__ void scan_pass2(const u16* __restrict__ LA,
                           const u16* __restrict__ BX,
                           const u16* __restrict__ CC,
                           const float* __restrict__ H0,
                           u16* __restrict__ Y)
{
    const int c = blockIdx.x >> 3;
    const int h = ((blockIdx.x & 7) << 8) + threadIdx.x;
    float hrun = H0[c * HID + h];
    size_t base = (size_t)c * CT * HID + h;
    for (int t = 0; t < CT; t++) {
        float a  = exp2f(bf2f(LA[base]));
        float bx = bf2f(BX[base]);
        hrun = fmaf(a, hrun, bx);
        Y[base] = f2bf(bf2f(CC[base]) * hrun);
        base += HID;
    }
}

// ---------------------------------------------------------------------------
// Kernel 5: out[t,:] = Y[t,:] @ W_out.T + x[t,:] @ W_skip.T + b_out
// One wave per 4 t-rows; W tiles in registers; shuffle-only reduction.
// ---------------------------------------------------------------------------
__launch_bounds__(256)
__global__ void out_kernel(const u16* __restrict__ Y,
                           const float* __restrict__ x,
                           const float* __restrict__ W_out,
                           const float* __restrict__ b_out,
                           const float* __restrict__ W_skip,
                           float* __restrict__ out)
{
    const int wave = threadIdx.x >> 6;
    const int lane = threadIdx.x & 63;
    const int t0 = (blockIdx.x * 4 + wave) * 4;     // 4 t-rows per wave

    float acc[4][NOBJ];
#pragma unroll
    for (int tt = 0; tt < 4; tt++)
#pragma unroll
        for (int o = 0; o < NOBJ; o++) acc[tt][o] = 0.f;

    // hidden part: HID/4 = 512 groups of 4, 64 lanes -> 8 iters
#pragma unroll 2
    for (int i = 0; i < 8; i++) {
        const int hv = (i * 64 + lane) * 4;
        float4 w[NOBJ];
#pragma unroll
        for (int o = 0; o < NOBJ; o++)
            w[o] = *(const float4*)(W_out + (size_t)o * HID + hv);
#pragma unroll
        for (int tt = 0; tt < 4; tt++) {
            u16x4 yv = *(const u16x4*)(Y + (size_t)(t0 + tt) * HID + hv);
            float y0 = bf2f(yv[0]), y1 = bf2f(yv[1]);
            float y2 = bf2f(yv[2]), y3 = bf2f(yv[3]);
#pragma unroll
            for (int o = 0; o < NOBJ; o++)
                acc[tt][o] += y0 * w[o].x + y1 * w[o].y +
                              y2 * w[o].z + y3 * w[o].w;
        }
    }
    // skip part: KOBS/4 = 128 groups -> 2 iters
#pragma unroll
    for (int i = 0; i < 2; i++) {
        const int kv = (i * 64 + lane) * 4;
        float4 w[NOBJ];
#pragma unroll
        for (int o = 0; o < NOBJ; o++)
            w[o] = *(const float4*)(W_skip + (size_t)o * KOBS + kv);
#pragma unroll
        for (int tt = 0; tt < 4; tt++) {
            float4 xv = *(const float4*)(x + (size_t)(t0 + tt) * KOBS + kv);
#pragma unroll
            for (int o = 0; o < NOBJ; o++)
                acc[tt][o] += xv.x * w[o].x + xv.y * w[o].y +
                              xv.z * w[o].z + xv.w * w[o].w;
        }
    }

    // butterfly reduce across 64 lanes
#pragma unroll
    for (int s = 32; s > 0; s >>= 1)
#pragma unroll
        for (int tt = 0; tt < 4; tt++)
#pragma unroll
            for (int o = 0; o < NOBJ; o++)
                acc[tt][o] += __shfl_xor(acc[tt][o], s, 64);

    if (lane == 0) {
#pragma unroll
        for (int tt = 0; tt < 4; tt++)
#pragma unroll
            for (int o = 0; o < NOBJ; o++)
                out[(size_t)(t0 + tt) * NOBJ + o] = acc[tt][o] + b_out[o];
    }
}

// ---------------------------------------------------------------------------
extern "C" void kernel_launch(void* const* d_in, const int* in_sizes, int n_in,
                              void* d_out, int out_size, void* d_ws, size_t ws_size,
                              hipStream_t stream)
{
    const float* x      = (const float*)d_in[0];
    const float* Win    = (const float*)d_in[1];
    const float* WB     = (const float*)d_in[2];
    const float* WC     = (const float*)d_in[3];
    const float* Wd     = (const float*)d_in[4];
    const float* A_log  = (const float*)d_in[5];
    const float* W_out  = (const float*)d_in[6];
    const float* b_out  = (const float*)d_in[7];
    const float* W_skip = (const float*)d_in[8];
    float* out = (float*)d_out;

    char* ws = (char*)d_ws;
    size_t off = 0;
    auto alloc = [&](size_t bytes) -> void* {
        void* p = (void*)(ws + off);
        off += (bytes + 255) & ~(size_t)255;
        return p;
    };

    u16*   x_bf = (u16*)  alloc((size_t)TT * KOBS * 2);        //  8.4 MB
    u16*   W_bf = (u16*)  alloc((size_t)4 * HID * KOBS * 2);   //  8.4 MB
    float* A_e  = (float*)alloc((size_t)HID * 4);              //  8 KB
    u16*   LA   = (u16*)  alloc((size_t)TT * HID * 2);         // 33.6 MB
    u16*   BX   = (u16*)  alloc((size_t)TT * HID * 2);         // 33.6 MB
    u16*   CC   = (u16*)  alloc((size_t)TT * HID * 2);         // 33.6 MB
    float* P    = (float*)alloc((size_t)NCH * HID * 4);        //  0.5 MB
    float* S    = (float*)alloc((size_t)NCH * HID * 4);        //  0.5 MB
    float* H0   = (float*)alloc((size_t)NCH * HID * 4);        //  0.5 MB
    u16*   Y    = (u16*)  alloc((size_t)TT * HID * 2);         // 33.6 MB
    (void)ws_size; (void)in_sizes; (void)n_in; (void)out_size;

    prep_kernel<<<2048, 256, 0, stream>>>(x, Win, WB, WC, Wd, A_log,
                                          x_bf, W_bf, A_e);
    gemm_fused<<<4096, 256, 0, stream>>>(x_bf, W_bf, A_e, BX, CC, LA, P, S);
    scan_combine<<<8, 256, 0, stream>>>(P, S, H0);
    scan_pass2<<<512, 256, 0, stream>>>(LA, BX, CC, H0, Y);
    out_kernel<<<512, 256, 0, stream>>>(Y, x, W_out, b_out, W_skip, out);
}